// Round 10
// baseline (88.331 us; speedup 1.0000x reference)
//
#include <hip/hip_runtime.h>
#include <hip/hip_fp16.h>

// Problem constants (from reference setup_inputs)
constexpr int Bn = 256;
constexpr int Nn = 16384;
constexpr int Hh = 96;
constexpr int Ww = 96;

constexpr int THREADS = 512;
constexpr int CHUNKS  = 4;                       // 1024 blocks = 4 per CU
constexpr int PER_THREAD = Nn / CHUNKS / THREADS;  // 8 corners per thread

// Plain fp16-pair LDS entries (4B): entry k of a padded row = (pad[2k], pad[2k+1]).
// Edge: 100 padded rows (2 top/bot) x 51 entries (50 real + 1 junk) = 5100
// Mask:  98 padded rows (1 top/bot) x 50 entries                    = 4900
// Total 10000 entries * 4B = 40000 B + 64 B reduce -> 4 blocks/CU -> 32 waves/CU.
constexpr int EPS = 51, MPS = 50;
constexpr int MOFF = 5100;
constexpr int TOT  = 10000;

static __device__ inline unsigned pack2(float x, float y)
{
    __half2 h = __float22half2_rn(make_float2(x, y));
    return *(unsigned*)&h;
}
static __device__ inline float2 unpack2(unsigned u)
{
    __half2 h = *(__half2*)&u;
    return __half22float2(h);
}

__global__ __launch_bounds__(THREADS, 8)
void geo_kernel(const float* __restrict__ corners,
                const float* __restrict__ edge,
                const float* __restrict__ mask,
                float2* __restrict__ partial)
{
    __shared__ unsigned sB[TOT];
    __shared__ float redE[THREADS / 64];
    __shared__ float redM[THREADS / 64];

    const int b     = blockIdx.x >> 2;           // CHUNKS == 4
    const int chunk = blockIdx.x & 3;
    const int tid   = threadIdx.x;

    // --- zero border entries (disjoint from interior fill below) ---
    {
        for (int i = tid; i < 784; i += THREADS) {
            int idx;
            if (i < 204) {                        // edge full pad rows 0,1,98,99
                int r = i / 51, c = i - 51 * r;
                idx = ((r < 2) ? r : (96 + r)) * EPS + c;
            } else if (i < 492) {                 // edge rows 2..97, entries {0,49,50}
                int j = i - 204; int r = j / 3; int c3 = j - 3 * r;
                int c = (c3 == 0) ? 0 : (48 + c3);
                idx = (r + 2) * EPS + c;
            } else if (i < 592) {                 // mask full pad rows 0,97
                int j = i - 492; int r = (j < 50) ? 0 : 97; int c = j % 50;
                idx = MOFF + r * MPS + c;
            } else {                              // mask rows 1..96, entries {0,49}
                int j = i - 592; int r = j >> 1; int c = (j & 1) ? 49 : 0;
                idx = MOFF + (r + 1) * MPS + c;
            }
            sB[idx] = 0u;
        }
    }

    // --- fill interiors: entry k (1..48) of padded row = image px (2k-2, 2k-1) ---
    {
        const float* ebase = edge + (size_t)b * Hh * Ww;
        const float* mbase = mask + (size_t)b * Hh * Ww;
        for (int i = tid; i < 2 * 96 * 48; i += THREADS) {
            int isMask = (i >= 96 * 48);
            int j = isMask ? (i - 96 * 48) : i;
            int r = j / 48;
            int k = j - 48 * r + 1;
            const float* src = isMask ? mbase : ebase;
            float2 v = *(const float2*)(src + r * Ww + 2 * k - 2);
            int idx = isMask ? (MOFF + (r + 1) * MPS + k) : ((r + 2) * EPS + k);
            sB[idx] = pack2(v.x, v.y);
        }
    }
    __syncthreads();

    // --- corner processing: 2 phases of 4 corners (keeps VGPR <= 64) ---
    const float4* c4 =
        (const float4*)(corners + (size_t)b * Nn * 2 + (size_t)chunk * (Nn / CHUNKS) * 2);
    float eAcc = 0.f, mAcc = 0.f;

#pragma unroll
    for (int ph = 0; ph < 2; ++ph) {
        float4 ca = c4[(2 * ph + 0) * THREADS + tid];
        float4 cb = c4[(2 * ph + 1) * THREADS + tid];
#pragma unroll
        for (int jj = 0; jj < 4; ++jj) {
            float cx, cy;
            if      (jj == 0) { cx = ca.x; cy = ca.y; }
            else if (jj == 1) { cx = ca.z; cy = ca.w; }
            else if (jj == 2) { cx = cb.x; cy = cb.y; }
            else              { cx = cb.z; cy = cb.w; }

            // ix = 96*cx - 0.5 (see reference algebra)
            float ix = fmaf(cx, 96.f, -0.5f);
            float iy = fmaf(cy, 96.f, -0.5f);
            float x0f = floorf(ix), y0f = floorf(iy);
            float wx = ix - x0f, wy = iy - y0f;
            int x0 = (int)x0f, y0 = (int)y0f;

            // ---- edge 4x4: padded px window pe..pe+3 per row ----
            int pe = x0 + 1;
            int s  = pe & 1;
            int e0 = pe >> 1;
            int rb = (y0 + 1) * EPS + e0;

            float h[4][3];
#pragma unroll
            for (int rr = 0; rr < 4; ++rr) {
                int base = rb + rr * EPS;
                unsigned u0 = sB[base];
                unsigned u1 = sB[base + 1];
                unsigned u2 = sB[base + 2];
                unsigned w0 = s ? ((u0 >> 16) | (u1 << 16)) : u0;
                unsigned w1 = s ? ((u1 >> 16) | (u2 << 16)) : u1;
                float2 f01 = unpack2(w0);
                float2 f23 = unpack2(w1);
                h[rr][0] = fmaf(wx, f01.y - f01.x, f01.x);
                h[rr][1] = fmaf(wx, f23.x - f01.y, f01.y);
                h[rr][2] = fmaf(wx, f23.y - f23.x, f23.x);
            }
            float best = fmaf(wy, h[1][0] - h[0][0], h[0][0]);
#pragma unroll
            for (int r = 0; r < 3; ++r)
#pragma unroll
                for (int k = 0; k < 3; ++k) {
                    if (r == 0 && k == 0) continue;
                    float v = fmaf(wy, h[r + 1][k] - h[r][k], h[r][k]);
                    best = fmaxf(best, v);
                }
            eAcc += best;

            // ---- mask 2x2: padded px pm..pm+1, rows y0+1, y0+2 ----
            int pm  = x0 + 2;
            int sm  = pm & 1;
            int em  = pm >> 1;
            int mb  = MOFF + (y0 + 1) * MPS + em;
            unsigned m0 = sB[mb],       m1 = sB[mb + 1];
            unsigned m2 = sB[mb + MPS], m3 = sB[mb + MPS + 1];
            unsigned wt = sm ? ((m0 >> 16) | (m1 << 16)) : m0;
            unsigned wb = sm ? ((m2 >> 16) | (m3 << 16)) : m2;
            float2 ft = unpack2(wt);
            float2 fb = unpack2(wb);
            float t = fmaf(wx, ft.y - ft.x, ft.x);
            float u = fmaf(wx, fb.y - fb.x, fb.x);
            float m = fmaf(wy, u - t, t);
            float d = m - 0.5f;
            mAcc = fmaf(d, d, mAcc);
        }
    }

    // --- reduce: wave shuffle, cross-wave via LDS, per-block partial ---
#pragma unroll
    for (int off = 32; off > 0; off >>= 1) {
        eAcc += __shfl_xor(eAcc, off);
        mAcc += __shfl_xor(mAcc, off);
    }
    const int wv = tid >> 6;
    const int ln = tid & 63;
    if (ln == 0) { redE[wv] = eAcc; redM[wv] = mAcc; }
    __syncthreads();

    if (tid == 0) {
        float e = 0.f, m = 0.f;
#pragma unroll
        for (int w = 0; w < THREADS / 64; ++w) { e += redE[w]; m += redM[w]; }
        partial[blockIdx.x] = make_float2(e, m);
    }
}

// Final reduction over the 1024 block partials; no atomics anywhere.
__global__ __launch_bounds__(1024)
void geo_reduce(const float2* __restrict__ partial, float* __restrict__ out)
{
    __shared__ double rE[16];
    __shared__ double rM[16];
    const int tid = threadIdx.x;
    float2 p = partial[tid];
    double e = (double)p.x, m = (double)p.y;
#pragma unroll
    for (int off = 32; off > 0; off >>= 1) {
        e += __shfl_xor(e, off);
        m += __shfl_xor(m, off);
    }
    if ((tid & 63) == 0) { rE[tid >> 6] = e; rM[tid >> 6] = m; }
    __syncthreads();
    if (tid == 0) {
        double se = 0.0, sm = 0.0;
#pragma unroll
        for (int w = 0; w < 16; ++w) { se += rE[w]; sm += rM[w]; }
        const double inv = 1.0 / (double)((long long)Bn * (long long)Nn);
        double edge_loss = 1.0 - se * inv;
        double mask_loss = sm * inv;
        out[0] = (float)(edge_loss + 2.0 * mask_loss);
    }
}

extern "C" void kernel_launch(void* const* d_in, const int* in_sizes, int n_in,
                              void* d_out, int out_size, void* d_ws, size_t ws_size,
                              hipStream_t stream)
{
    const float* corners = (const float*)d_in[0];
    const float* edge    = (const float*)d_in[1];
    const float* mask    = (const float*)d_in[2];
    float* out      = (float*)d_out;
    float2* partial = (float2*)d_ws;

    geo_kernel<<<Bn * CHUNKS, THREADS, 0, stream>>>(corners, edge, mask, partial);
    geo_reduce<<<1, 1024, 0, stream>>>(partial, out);
}

// Round 11
// 44.722 us; speedup vs baseline: 1.9751x; 1.9751x over previous
//
#include <hip/hip_runtime.h>
#include <hip/hip_fp16.h>

// Problem constants (from reference setup_inputs)
constexpr int Bn = 256;
constexpr int Nn = 16384;
constexpr int Hh = 96;
constexpr int Ww = 96;

constexpr int THREADS = 512;
constexpr int CHUNKS  = 4;                       // 1024 blocks = 4 per CU
// Edge-only LDS, dup-pair fp16: entry (r,c) = (pad[c], pad[c+1]) of padded
// row r (pad = 2 zeros each side). 100 x 100 entries x 4 B = 40,000 B
// -> 4 blocks/CU -> 32 waves/CU. Mask is sampled from global (L1/L2-resident).
constexpr int EPS = 100;
constexpr int ESZ = 100 * 100;

static __device__ inline float2 unpack2(__half2 h) { return __half22float2(h); }

__global__ __launch_bounds__(THREADS, 8)
void geo_kernel(const float* __restrict__ corners,
                const float* __restrict__ edge,
                const float* __restrict__ mask,
                float2* __restrict__ partial)
{
    __shared__ __half2 sE[ESZ];                  // 40,000 B; reused for reduce

    const int b     = blockIdx.x >> 2;           // CHUNKS == 4
    const int chunk = blockIdx.x & 3;
    const int tid   = threadIdx.x;

    // --- zero border entries (rows 0,1,98,99 full; cols {0,98,99} of 2..97) ---
    {
        const __half2 z2 = __halves2half2(__ushort_as_half(0), __ushort_as_half(0));
        for (int i = tid; i < 688; i += THREADS) {
            int idx;
            if (i < 400) {                        // pad rows 0,1,98,99
                idx = (i < 200) ? i : (9600 + i); // 9800 + (i-200)
            } else {                              // rows 2..97, cols {0,98,99}
                int j = i - 400; int r = j / 3; int c3 = j - 3 * r;
                int c = (c3 == 0) ? 0 : (97 + c3);
                idx = (r + 2) * EPS + c;
            }
            sE[idx] = z2;
        }
    }

    // --- fill interior with dup-pair fp16 (cols 1..97; disjoint from border) ---
    {
        const float* ebase = edge + (size_t)b * Hh * Ww;
        for (int i = tid; i < 96 * 48; i += THREADS) {
            int r = i / 48;
            int j = i - 48 * r;
            const float* erow = ebase + r * Ww;
            float2 ae = *(const float2*)(erow + 2 * j);
            float ne = (2 * j + 2 < Ww) ? erow[2 * j + 2] : 0.f;
            int base = (r + 2) * EPS + 2 * j + 2;
            sE[base]     = __float22half2_rn(make_float2(ae.x, ae.y));
            sE[base + 1] = __float22half2_rn(make_float2(ae.y, ne));
            if (j == 0)
                sE[(r + 2) * EPS + 1] = __float22half2_rn(make_float2(0.f, ae.x));
        }
    }
    __syncthreads();

    const float* mbase = mask + (size_t)b * Hh * Ww;
    const float4* c4 =
        (const float4*)(corners + (size_t)b * Nn * 2 + (size_t)chunk * (Nn / CHUNKS) * 2);

    float eAcc = 0.f, mAcc = 0.f;

    // --- 2 phases x 4 corners; named scalars ONLY (no arrays -> no scratch) ---
#pragma unroll
    for (int ph = 0; ph < 2; ++ph) {
        float4 ca = c4[(2 * ph + 0) * THREADS + tid];
        float4 cb4 = c4[(2 * ph + 1) * THREADS + tid];
#pragma unroll
        for (int jj = 0; jj < 4; ++jj) {
            float cx, cy;
            if      (jj == 0) { cx = ca.x;  cy = ca.y;  }
            else if (jj == 1) { cx = ca.z;  cy = ca.w;  }
            else if (jj == 2) { cx = cb4.x; cy = cb4.y; }
            else              { cx = cb4.z; cy = cb4.w; }

            // ix = ((gx+1)*W - 1)*0.5, gx = 2*cx - 1  =>  ix = 96*cx - 0.5
            float ix = fmaf(cx, 96.f, -0.5f);
            float iy = fmaf(cy, 96.f, -0.5f);
            float x0f = floorf(ix), y0f = floorf(iy);
            float wx = ix - x0f, wy = iy - y0f;
            int x0 = (int)x0f, y0 = (int)y0f;

            // ---- edge 4x4 from LDS: 4 x ds_read2_b32, no selects ----
            int cb = (y0 + 1) * EPS + (x0 + 1);
            __half2 a0 = sE[cb],           d0 = sE[cb + 2];
            __half2 a1 = sE[cb + EPS],     d1 = sE[cb + EPS + 2];
            __half2 a2 = sE[cb + 2 * EPS], d2 = sE[cb + 2 * EPS + 2];
            __half2 a3 = sE[cb + 3 * EPS], d3 = sE[cb + 3 * EPS + 2];

            float2 A0 = unpack2(a0), D0 = unpack2(d0);
            float2 A1 = unpack2(a1), D1 = unpack2(d1);
            float2 A2 = unpack2(a2), D2 = unpack2(d2);
            float2 A3 = unpack2(a3), D3 = unpack2(d3);

            float h00 = fmaf(wx, A0.y - A0.x, A0.x);
            float h01 = fmaf(wx, D0.x - A0.y, A0.y);
            float h02 = fmaf(wx, D0.y - D0.x, D0.x);
            float h10 = fmaf(wx, A1.y - A1.x, A1.x);
            float h11 = fmaf(wx, D1.x - A1.y, A1.y);
            float h12 = fmaf(wx, D1.y - D1.x, D1.x);
            float h20 = fmaf(wx, A2.y - A2.x, A2.x);
            float h21 = fmaf(wx, D2.x - A2.y, A2.y);
            float h22 = fmaf(wx, D2.y - D2.x, D2.x);
            float h30 = fmaf(wx, A3.y - A3.x, A3.x);
            float h31 = fmaf(wx, D3.x - A3.y, A3.y);
            float h32 = fmaf(wx, D3.y - D3.x, D3.x);

            float v00 = fmaf(wy, h10 - h00, h00);
            float v01 = fmaf(wy, h11 - h01, h01);
            float v02 = fmaf(wy, h12 - h02, h02);
            float v10 = fmaf(wy, h20 - h10, h10);
            float v11 = fmaf(wy, h21 - h11, h11);
            float v12 = fmaf(wy, h22 - h12, h12);
            float v20 = fmaf(wy, h30 - h20, h20);
            float v21 = fmaf(wy, h31 - h21, h21);
            float v22 = fmaf(wy, h32 - h22, h22);

            float best = fmaxf(fmaxf(fmaxf(v00, v01), fmaxf(v02, v10)),
                               fmaxf(fmaxf(v11, v12), fmaxf(fmaxf(v20, v21), v22)));
            eAcc += best;

            // ---- mask 2x2 from GLOBAL fp32 (clamped loads + zero-select) ----
            int x1 = x0 + 1, y1 = y0 + 1;
            int xc0 = min(max(x0, 0), 95), xc1 = min(max(x1, 0), 95);
            int yc0 = min(max(y0, 0), 95), yc1 = min(max(y1, 0), 95);
            bool vx0 = (unsigned)x0 < 96u, vx1 = (unsigned)x1 < 96u;
            bool vy0 = (unsigned)y0 < 96u, vy1 = (unsigned)y1 < 96u;
            const float* r0p = mbase + yc0 * Ww;
            const float* r1p = mbase + yc1 * Ww;
            float l00 = r0p[xc0], l01 = r0p[xc1];
            float l10 = r1p[xc0], l11 = r1p[xc1];
            float t00 = (vx0 && vy0) ? l00 : 0.f;
            float t01 = (vx1 && vy0) ? l01 : 0.f;
            float t10 = (vx0 && vy1) ? l10 : 0.f;
            float t11 = (vx1 && vy1) ? l11 : 0.f;
            float t = fmaf(wx, t01 - t00, t00);
            float u = fmaf(wx, t11 - t10, t10);
            float m = fmaf(wy, u - t, t);
            float d = m - 0.5f;
            mAcc = fmaf(d, d, mAcc);
        }
    }

    // --- reduce: wave shuffle, cross-wave via reused LDS ---
#pragma unroll
    for (int off = 32; off > 0; off >>= 1) {
        eAcc += __shfl_xor(eAcc, off);
        mAcc += __shfl_xor(mAcc, off);
    }
    __syncthreads();                       // done reading sE; reuse as scratch
    float* red = (float*)sE;               // [0..7]=edge, [8..15]=mask
    const int wv = tid >> 6;
    const int ln = tid & 63;
    if (ln == 0) { red[wv] = eAcc; red[8 + wv] = mAcc; }
    __syncthreads();

    if (tid == 0) {
        float e = 0.f, m = 0.f;
#pragma unroll
        for (int w = 0; w < THREADS / 64; ++w) { e += red[w]; m += red[8 + w]; }
        partial[blockIdx.x] = make_float2(e, m);
    }
}

// Final reduction over the 1024 block partials; no atomics anywhere.
__global__ __launch_bounds__(1024)
void geo_reduce(const float2* __restrict__ partial, float* __restrict__ out)
{
    __shared__ double rE[16];
    __shared__ double rM[16];
    const int tid = threadIdx.x;
    float2 p = partial[tid];
    double e = (double)p.x, m = (double)p.y;
#pragma unroll
    for (int off = 32; off > 0; off >>= 1) {
        e += __shfl_xor(e, off);
        m += __shfl_xor(m, off);
    }
    if ((tid & 63) == 0) { rE[tid >> 6] = e; rM[tid >> 6] = m; }
    __syncthreads();
    if (tid == 0) {
        double se = 0.0, sm = 0.0;
#pragma unroll
        for (int w = 0; w < 16; ++w) { se += rE[w]; sm += rM[w]; }
        const double inv = 1.0 / (double)((long long)Bn * (long long)Nn);
        double edge_loss = 1.0 - se * inv;
        double mask_loss = sm * inv;
        out[0] = (float)(edge_loss + 2.0 * mask_loss);
    }
}

extern "C" void kernel_launch(void* const* d_in, const int* in_sizes, int n_in,
                              void* d_out, int out_size, void* d_ws, size_t ws_size,
                              hipStream_t stream)
{
    const float* corners = (const float*)d_in[0];
    const float* edge    = (const float*)d_in[1];
    const float* mask    = (const float*)d_in[2];
    float* out      = (float*)d_out;
    float2* partial = (float2*)d_ws;

    geo_kernel<<<Bn * CHUNKS, THREADS, 0, stream>>>(corners, edge, mask, partial);
    geo_reduce<<<1, 1024, 0, stream>>>(partial, out);
}

// Round 12
// 25.235 us; speedup vs baseline: 3.5003x; 1.7722x over previous
//
#include <hip/hip_runtime.h>
#include <hip/hip_fp16.h>

// Problem constants (from reference setup_inputs)
constexpr int Bn = 256;
constexpr int Nn = 16384;
constexpr int Hh = 96;
constexpr int Ww = 96;

constexpr int THREADS = 1024;
constexpr int CHUNKS  = 2;                 // 512 blocks -> 2 per CU -> 32 waves/CU

// Dup-pair fp16 LDS entries (4B): entry c = (pad[c], pad[c+1]).
//   Edge: pad rows 0..99 (2-zero pad each side), 100x100 = 10000 entries
//   Mask: pad rows 1..98 stored as s-rows 0..97,   98x100 =  9800 entries
// Total 19800 x 4B = 79.2 KB -> 2 blocks/CU.
// Per corner: edge 4x4 = 4 ds_read2_b32, mask 2x2 = 1 ds_read2_b32.
constexpr int MOFF = 10000;
constexpr int TOTENT = 19800;

static __device__ inline float2 up2(__half2 h) { return __half22float2(h); }

// ---- per-corner macros (named scalars only; no arrays -> no scratch) ----
#define ADDR(sfx, CX, CY)                                                   \
    float ix##sfx = fmaf(CX, 96.f, -0.5f);                                  \
    float iy##sfx = fmaf(CY, 96.f, -0.5f);                                  \
    float fx##sfx = floorf(ix##sfx), fy##sfx = floorf(iy##sfx);             \
    float wx##sfx = ix##sfx - fx##sfx, wy##sfx = iy##sfx - fy##sfx;         \
    int v##sfx  = (int)fy##sfx * 100 + (int)fx##sfx;                        \
    int cb##sfx = v##sfx + 101;                                             \
    int c3##sfx = v##sfx + 401;                                             \
    int mb##sfx = v##sfx + MOFF + 102;

#define ISSUE(sfx)                                                          \
    __half2 a0##sfx = sB[cb##sfx],       d0##sfx = sB[cb##sfx + 2];         \
    __half2 a1##sfx = sB[cb##sfx + 100], d1##sfx = sB[cb##sfx + 102];       \
    __half2 a2##sfx = sB[cb##sfx + 200], d2##sfx = sB[cb##sfx + 202];       \
    __half2 a3##sfx = sB[c3##sfx],       d3##sfx = sB[c3##sfx + 2];         \
    __half2 ma##sfx = sB[mb##sfx],       mc##sfx = sB[mb##sfx + 100];

#define COMPUTE(sfx)                                                        \
    {                                                                       \
        float2 A0 = up2(a0##sfx), D0 = up2(d0##sfx);                        \
        float2 A1 = up2(a1##sfx), D1 = up2(d1##sfx);                        \
        float2 A2 = up2(a2##sfx), D2 = up2(d2##sfx);                        \
        float2 A3 = up2(a3##sfx), D3 = up2(d3##sfx);                        \
        float wx = wx##sfx, wy = wy##sfx;                                   \
        float h00 = fmaf(wx, A0.y - A0.x, A0.x);                            \
        float h01 = fmaf(wx, D0.x - A0.y, A0.y);                            \
        float h02 = fmaf(wx, D0.y - D0.x, D0.x);                            \
        float h10 = fmaf(wx, A1.y - A1.x, A1.x);                            \
        float h11 = fmaf(wx, D1.x - A1.y, A1.y);                            \
        float h12 = fmaf(wx, D1.y - D1.x, D1.x);                            \
        float h20 = fmaf(wx, A2.y - A2.x, A2.x);                            \
        float h21 = fmaf(wx, D2.x - A2.y, A2.y);                            \
        float h22 = fmaf(wx, D2.y - D2.x, D2.x);                            \
        float h30 = fmaf(wx, A3.y - A3.x, A3.x);                            \
        float h31 = fmaf(wx, D3.x - A3.y, A3.y);                            \
        float h32 = fmaf(wx, D3.y - D3.x, D3.x);                            \
        float v00 = fmaf(wy, h10 - h00, h00);                               \
        float v01 = fmaf(wy, h11 - h01, h01);                               \
        float v02 = fmaf(wy, h12 - h02, h02);                               \
        float v10 = fmaf(wy, h20 - h10, h10);                               \
        float v11 = fmaf(wy, h21 - h11, h11);                               \
        float v12 = fmaf(wy, h22 - h12, h12);                               \
        float v20 = fmaf(wy, h30 - h20, h20);                               \
        float v21 = fmaf(wy, h31 - h21, h21);                               \
        float v22 = fmaf(wy, h32 - h22, h22);                               \
        float best = fmaxf(fmaxf(fmaxf(v00, v01), fmaxf(v02, v10)),         \
                           fmaxf(fmaxf(v11, v12),                           \
                                 fmaxf(fmaxf(v20, v21), v22)));             \
        eAcc += best;                                                       \
        float2 qa = up2(ma##sfx), qc = up2(mc##sfx);                        \
        float t = fmaf(wx, qa.y - qa.x, qa.x);                              \
        float u = fmaf(wx, qc.y - qc.x, qc.x);                              \
        float m = fmaf(wy, u - t, t);                                       \
        float d = m - 0.5f;                                                 \
        mAcc = fmaf(d, d, mAcc);                                            \
    }

__global__ __launch_bounds__(THREADS, 8)
void geo_kernel(const float* __restrict__ corners,
                const float* __restrict__ edge,
                const float* __restrict__ mask,
                float2* __restrict__ partial)
{
    __shared__ __half2 sB[TOTENT];
    __shared__ float redE[THREADS / 64];
    __shared__ float redM[THREADS / 64];

    const int b     = blockIdx.x >> 1;     // CHUNKS == 2
    const int chunk = blockIdx.x & 1;
    const int tid   = threadIdx.x;

    // --- zero border entries (disjoint from interior fill) ---
    {
        const __half2 z2 = __halves2half2(__ushort_as_half(0), __ushort_as_half(0));
        for (int i = tid; i < 1176; i += THREADS) {
            int idx;
            if (i < 200)        idx = i;                          // edge pad rows 0,1
            else if (i < 400)   idx = 9600 + i;                   // edge pad rows 98,99
            else if (i < 500)   idx = MOFF + (i - 400);           // mask s-row 0
            else if (i < 600)   idx = MOFF + 9200 + i;            // mask s-row 97
            else if (i < 888) { int k = i - 600; int r = k / 3; int c3 = k - 3 * r;
                                int c = (c3 == 0) ? 0 : (97 + c3);
                                idx = (r + 2) * 100 + c; }        // edge rows 2..97
            else              { int k = i - 888; int r = k / 3; int c3 = k - 3 * r;
                                int c = (c3 == 0) ? 0 : (97 + c3);
                                idx = MOFF + (r + 1) * 100 + c; } // mask s-rows 1..96
            sB[idx] = z2;
        }
    }

    // --- fill interiors with dup-pair fp16 (disjoint from borders) ---
    {
        const float* ebase = edge + (size_t)b * Hh * Ww;
        const float* mbase = mask + (size_t)b * Hh * Ww;
        for (int i = tid; i < 96 * 48; i += THREADS) {
            int r = i / 48;
            int j = i - 48 * r;
            const float* erow = ebase + r * Ww;
            const float* mrow = mbase + r * Ww;
            float2 ae = *(const float2*)(erow + 2 * j);
            float2 am = *(const float2*)(mrow + 2 * j);
            float ne = (2 * j + 2 < Ww) ? erow[2 * j + 2] : 0.f;
            float nm = (2 * j + 2 < Ww) ? mrow[2 * j + 2] : 0.f;
            int eb2 = (r + 2) * 100 + 2 * j + 2;
            sB[eb2]     = __float22half2_rn(make_float2(ae.x, ae.y));
            sB[eb2 + 1] = __float22half2_rn(make_float2(ae.y, ne));
            int mb2 = MOFF + (r + 1) * 100 + 2 * j + 2;
            sB[mb2]     = __float22half2_rn(make_float2(am.x, am.y));
            sB[mb2 + 1] = __float22half2_rn(make_float2(am.y, nm));
            if (j == 0) {
                sB[(r + 2) * 100 + 1]        = __float22half2_rn(make_float2(0.f, ae.x));
                sB[MOFF + (r + 1) * 100 + 1] = __float22half2_rn(make_float2(0.f, am.x));
            }
        }
    }
    __syncthreads();

    // --- corner loop: 4 float4 (8 corners), pairwise software-pipelined ---
    const float4* c4 =
        (const float4*)(corners + (size_t)b * Nn * 2 + (size_t)chunk * (Nn / CHUNKS) * 2);
    float eAcc = 0.f, mAcc = 0.f;

    float4 nxt = c4[tid];
#pragma unroll
    for (int k = 0; k < 4; ++k) {
        float4 cur = nxt;
        if (k < 3) nxt = c4[(k + 1) * THREADS + tid];   // prefetch next pair

        ADDR(A, cur.x, cur.y)
        ISSUE(A)                      // 5 ds_read2 for corner A in flight
        ADDR(B, cur.z, cur.w)
        ISSUE(B)                      // 5 more for corner B in flight
        COMPUTE(A)                    // waits only on A's reads
        COMPUTE(B)
    }

    // --- reduce: wave shuffle, cross-wave via LDS, per-block partial ---
#pragma unroll
    for (int off = 32; off > 0; off >>= 1) {
        eAcc += __shfl_xor(eAcc, off);
        mAcc += __shfl_xor(mAcc, off);
    }
    const int wv = tid >> 6;
    const int ln = tid & 63;
    if (ln == 0) { redE[wv] = eAcc; redM[wv] = mAcc; }
    __syncthreads();

    if (tid == 0) {
        float e = 0.f, m = 0.f;
#pragma unroll
        for (int w = 0; w < THREADS / 64; ++w) { e += redE[w]; m += redM[w]; }
        partial[blockIdx.x] = make_float2(e, m);
    }
}

// Final reduction over the 512 block partials; no atomics anywhere.
__global__ __launch_bounds__(512)
void geo_reduce(const float2* __restrict__ partial, float* __restrict__ out)
{
    __shared__ double rE[8];
    __shared__ double rM[8];
    const int tid = threadIdx.x;
    float2 p = partial[tid];
    double e = (double)p.x, m = (double)p.y;
#pragma unroll
    for (int off = 32; off > 0; off >>= 1) {
        e += __shfl_xor(e, off);
        m += __shfl_xor(m, off);
    }
    if ((tid & 63) == 0) { rE[tid >> 6] = e; rM[tid >> 6] = m; }
    __syncthreads();
    if (tid == 0) {
        double se = 0.0, sm = 0.0;
#pragma unroll
        for (int w = 0; w < 8; ++w) { se += rE[w]; sm += rM[w]; }
        const double inv = 1.0 / (double)((long long)Bn * (long long)Nn);
        double edge_loss = 1.0 - se * inv;
        double mask_loss = sm * inv;
        out[0] = (float)(edge_loss + 2.0 * mask_loss);
    }
}

extern "C" void kernel_launch(void* const* d_in, const int* in_sizes, int n_in,
                              void* d_out, int out_size, void* d_ws, size_t ws_size,
                              hipStream_t stream)
{
    const float* corners = (const float*)d_in[0];
    const float* edge    = (const float*)d_in[1];
    const float* mask    = (const float*)d_in[2];
    float* out      = (float*)d_out;
    float2* partial = (float2*)d_ws;

    geo_kernel<<<Bn * CHUNKS, THREADS, 0, stream>>>(corners, edge, mask, partial);
    geo_reduce<<<1, 512, 0, stream>>>(partial, out);
}